// Round 3
// baseline (164.818 us; speedup 1.0000x reference)
//
#include <hip/hip_runtime.h>
#include <hip/hip_bf16.h>
#include <stdint.h>

// Attention fwd: B=2, N=2048, D=768, H=12, Dh=64, INNER=768
// R16 = gemms reverted byte-exact to R13 (R15 pipeline regressed them +6.7us)
// + attn_k kv-SPLIT wave specialization: wave (qh=w>>1, kh=w&1) owns
// 32 q-rows x 32 kv-rows. Same MFMA/exp count per wave-iter, but LDS
// ds_read_b128 count HALVES (4 kf + 4 bv vs 8+8) -- attn was LDS-read-pipe
// bound (~58% busy incl. 3.1M conflict cycles). End-of-kernel partial-O/lp
// exchange between wave pairs via LDS scratch (Ks reused). attn keeps R15's
// triple-buffer counted-vmcnt staging (proven -1.8us).

typedef __attribute__((ext_vector_type(8))) short bf16x8;
typedef __attribute__((ext_vector_type(4))) float f32x4;
typedef __attribute__((address_space(3))) unsigned int lds_uint;
typedef __attribute__((address_space(1))) const unsigned int g_uint;

__device__ __forceinline__ short f2bf(float f) {
    union { float f; uint32_t u; } x; x.f = f;
    uint32_t r = (x.u + 0x7fffu + ((x.u >> 16) & 1u)) >> 16;
    return (short)r;
}
__device__ __forceinline__ float exp2fast(float x) {
#if __has_builtin(__builtin_amdgcn_exp2f)
    return __builtin_amdgcn_exp2f(x);
#else
    return __expf(x * 0.6931471805599453f);
#endif
}
__device__ __forceinline__ void gl_lds16(const void* g, void* l) {
    __builtin_amdgcn_global_load_lds((g_uint*)g, (lds_uint*)l, 16, 0, 0);
}
#define WAITCNT_VM(N) asm volatile("s_waitcnt vmcnt(" #N ")" ::: "memory")
#define BARRIER_FENCED() do { __builtin_amdgcn_s_barrier(); \
                              asm volatile("" ::: "memory"); } while (0)

// ---------------------------------------------------------------------------
// 64x64 fp32->bf16 transpose tile (shared by prep_k / tr_w)
// ---------------------------------------------------------------------------
__device__ __forceinline__ void tr_tile(const float* __restrict__ W,
                                        short* __restrict__ Wt, int K, int N,
                                        int n0, int k0, int t, short* S) {
    {
        int kl = t >> 2, ng = t & 3;
        const float* src = W + (size_t)(k0 + kl) * N + n0 + ng * 16;
        #pragma unroll
        for (int j = 0; j < 16; j += 4) {
            float4 f = *(const float4*)(src + j);
            S[(ng*16 + j + 0) * 65 + kl] = f2bf(f.x);
            S[(ng*16 + j + 1) * 65 + kl] = f2bf(f.y);
            S[(ng*16 + j + 2) * 65 + kl] = f2bf(f.z);
            S[(ng*16 + j + 3) * 65 + kl] = f2bf(f.w);
        }
    }
    __syncthreads();
    {
        int nl = t >> 2, kg = t & 3;
        short* dst = Wt + (size_t)(n0 + nl) * K + k0 + kg * 16;
        #pragma unroll
        for (int j = 0; j < 16; j += 4) {
            short4 s4;
            s4.x = S[nl*65 + kg*16 + j + 0];
            s4.y = S[nl*65 + kg*16 + j + 1];
            s4.z = S[nl*65 + kg*16 + j + 2];
            s4.w = S[nl*65 + kg*16 + j + 3];
            *(short4*)(dst + j) = s4;
        }
    }
}

// fused prep: [0,1536) x->bf16 ; [1536,1968) w_qkv^T ; [1968,2112) w_out^T
__global__ __launch_bounds__(256)
void prep_k(const float* __restrict__ x, short* __restrict__ Xb,
            const float* __restrict__ Wq, short* __restrict__ Wqt,
            const float* __restrict__ Wo, short* __restrict__ Wot)
{
    __shared__ short S[64 * 65];
    const int t = threadIdx.x;
    if (blockIdx.x < 1536) {
        int i = (blockIdx.x * 256 + t) * 8;
        float4 f0 = *(const float4*)(x + i);
        float4 f1 = *(const float4*)(x + i + 4);
        short s[8];
        s[0]=f2bf(f0.x); s[1]=f2bf(f0.y); s[2]=f2bf(f0.z); s[3]=f2bf(f0.w);
        s[4]=f2bf(f1.x); s[5]=f2bf(f1.y); s[6]=f2bf(f1.z); s[7]=f2bf(f1.w);
        *(uint4*)(Xb + i) = *(uint4*)s;
        return;
    }
    if (blockIdx.x < 1968) {
        const int b2 = blockIdx.x - 1536;                  // N=2304, K=768
        tr_tile(Wq, Wqt, 768, 2304, (b2 % 36) * 64, (b2 / 36) * 64, t, S);
    } else {
        const int b3 = blockIdx.x - 1968;                  // N=768, K=768
        tr_tile(Wo, Wot, 768, 768, (b3 % 12) * 64, (b3 / 12) * 64, t, S);
    }
}

// standalone w_out transpose (fallback when Wot must alias Wqt)
__global__ __launch_bounds__(256)
void tr_w(const float* __restrict__ W, short* __restrict__ Wt, int K, int N) {
    __shared__ short S[64 * 65];
    tr_tile(W, Wt, K, N, blockIdx.x * 64, blockIdx.y * 64, threadIdx.x, S);
}

// ---------------------------------------------------------------------------
// QKV GEMM (R13, proven): 128x96 tiles, 768 blocks = 3/CU, double-buffered DMA.
// [4096x768]bf16 @ Wqt[2304x768]^T + b -> Qb(pre-scaled)/Kb/Vt bf16
// Vt layout TILED: Vt[bh][kt][d][n&63] (64x64 tiles, 8KB, dense windows)
// ---------------------------------------------------------------------------
__global__ __launch_bounds__(256)
void gemm_qkv(const short* __restrict__ A, const short* __restrict__ Bt,
              const float* __restrict__ bias,
              short* __restrict__ Qb, short* __restrict__ Kb, short* __restrict__ Vt)
{
    __shared__ short As[2][128 * 32];  // 512 chunks of 16B each buffer
    __shared__ short Bs[2][96 * 32];   // 384 chunks
    const int tid = threadIdx.x, lane = tid & 63, w = tid >> 6;
    const int wm = w >> 1, wn = w & 1, quad = lane >> 4, lcol = lane & 15;
    const int bm = blockIdx.y * 128, bn = blockIdx.x * 96;

    f32x4 acc[4][3];
    #pragma unroll
    for (int i = 0; i < 4; i++)
        #pragma unroll
        for (int j = 0; j < 3; j++) acc[i][j] = (f32x4){0.f, 0.f, 0.f, 0.f};

    // stage tile 0 into buffer 0
    {
        #pragma unroll
        for (int i = 0; i < 2; i++) {
            int c = tid + i * 256, row = c >> 2, cs = c & 3;
            gl_lds16(A + (size_t)(bm + row) * 768 + cs * 8, As[0] + c * 8);
        }
        int c = tid, row = c >> 2, cs = c & 3;
        gl_lds16(Bt + (size_t)(bn + row) * 768 + cs * 8, Bs[0] + c * 8);
        if (tid < 128) {
            int c2 = 256 + tid, row2 = c2 >> 2, cs2 = c2 & 3;
            gl_lds16(Bt + (size_t)(bn + row2) * 768 + cs2 * 8, Bs[0] + c2 * 8);
        }
    }
    __syncthreads();

    for (int it = 0; it < 24; it++) {
        const int p = it & 1;
        if (it < 23) {                 // prefetch next k-tile into alt buffer
            int kt = (it + 1) * 32;
            #pragma unroll
            for (int i = 0; i < 2; i++) {
                int c = tid + i * 256, row = c >> 2, cs = c & 3;
                gl_lds16(A + (size_t)(bm + row) * 768 + kt + cs * 8, As[p ^ 1] + c * 8);
            }
            int c = tid, row = c >> 2, cs = c & 3;
            gl_lds16(Bt + (size_t)(bn + row) * 768 + kt + cs * 8, Bs[p ^ 1] + c * 8);
            if (tid < 128) {
                int c2 = 256 + tid, row2 = c2 >> 2, cs2 = c2 & 3;
                gl_lds16(Bt + (size_t)(bn + row2) * 768 + kt + cs2 * 8, Bs[p ^ 1] + c2 * 8);
            }
        }
        bf16x8 a[4], b[3];
        #pragma unroll
        for (int tm = 0; tm < 4; tm++)
            a[tm] = *(const bf16x8*)(As[p] + (wm*64 + tm*16 + lcol) * 32 + quad * 8);
        #pragma unroll
        for (int tn = 0; tn < 3; tn++)
            b[tn] = *(const bf16x8*)(Bs[p] + (wn*48 + tn*16 + lcol) * 32 + quad * 8);
        #pragma unroll
        for (int tm = 0; tm < 4; tm++)
            #pragma unroll
            for (int tn = 0; tn < 3; tn++)
                acc[tm][tn] = __builtin_amdgcn_mfma_f32_16x16x32_bf16(a[tm], b[tn], acc[tm][tn], 0, 0, 0);
        __syncthreads();               // drains prefetch DMA + guards buffer swap
    }

    const float SCLQ = 0.18033688011112042f;   // 0.125 * log2(e) folded into Q
    #pragma unroll
    for (int tm = 0; tm < 4; tm++) {
        #pragma unroll
        for (int tn = 0; tn < 3; tn++) {
            int col = bn + wn*48 + tn*16 + lcol;
            float bv = bias[col];
            int which = (col >= 1536) ? 2 : (col >= 768 ? 1 : 0);
            int cc = col - which * 768;
            int h = cc >> 6, d = cc & 63;
            int rowbase = bm + wm*64 + tm*16 + quad*4;
            int bb = rowbase >> 11, n0 = rowbase & 2047;
            int bh = bb * 12 + h;
            if (which == 2) {                 // V: tiled V^T store, dense window
                short4 s4;
                s4.x = f2bf(acc[tm][tn][0] + bv);
                s4.y = f2bf(acc[tm][tn][1] + bv);
                s4.z = f2bf(acc[tm][tn][2] + bv);
                s4.w = f2bf(acc[tm][tn][3] + bv);
                *(short4*)(Vt + (((size_t)bh*32 + (n0 >> 6))*64 + d)*64 + (n0 & 63)) = s4;
            } else {
                #pragma unroll
                for (int reg = 0; reg < 4; reg++) {
                    float v = acc[tm][tn][reg] + bv;
                    if (which == 0) v *= SCLQ;
                    short* dst = (which == 0) ? Qb : Kb;
                    dst[((size_t)bh*2048 + n0 + reg)*64 + d] = f2bf(v);
                }
            }
        }
    }
}

// ---------------------------------------------------------------------------
// Flash attention R16: kv-split wave specialization.
// Wave (qh=w>>1, kh=w&1): 32 q-rows [qh*32,+32) x 32 kv-rows [kh*32,+32).
// Per wave-iter: 4 kf ds_reads + 8 QK MFMA, 4 bv ds_reads + 8 PV MFMA
// (LDS reads HALVED vs R15). In-register P transpose identical to R14's
// verified construction (per qs: X[0],X[1],Y[0],Y[1] + 2 permlane16_swap;
// pa holds kv_local = bitrev2(quad)*8+j; V chunk = kh*4+bitrev2(quad)).
// End: partial O/lp exchange between wave pairs (kh=1 -> LDS -> kh=0).
// Triple-buffered staging with counted vmcnt(4) (R15, proven).
// ---------------------------------------------------------------------------
__global__ __launch_bounds__(256)
void attn_k(const short* __restrict__ Q, const short* __restrict__ K,
            const short* __restrict__ Vt, short* __restrict__ Ab)
{
    __shared__ __align__(16) short Ks[3][4096];   // [kv][d] xor-swizzled chunks
    __shared__ __align__(16) short Vs[3][4096];   // [d][kv] xor-swizzled chunks

    const int tid = threadIdx.x, lane = tid & 63, w = tid >> 6;
    const int quad = lane >> 4, lcol = lane & 15;
    const int qh = w >> 1, kh = w & 1;
    const int bid = blockIdx.x;
    const int bh = bid % 24, qt = bid / 24;
    const int b = bh / 12, h = bh - b * 12;

    const short* Kg = K  + (size_t)bh * 131072;   // [n][d] rows, tile = 8KB
    const short* Vg = Vt + (size_t)bh * 131072;   // tiled [kt][d][n64], 8KB

    bf16x8 qf[2][2];                    // 32 q rows of this wave
    {
        const short* Qg = Q + ((size_t)bh * 2048 + (size_t)qt * 64 + qh * 32) * 64;
        #pragma unroll
        for (int qs = 0; qs < 2; qs++)
            #pragma unroll
            for (int ks = 0; ks < 2; ks++)
                qf[qs][ks] = *(const bf16x8*)(Qg + (qs*16 + lcol) * 64 + ks*32 + quad*8);
    }

    // stage tiles 0,1 (4 DMA/wave/tile, uniform)
    #pragma unroll
    for (int t0 = 0; t0 < 2; t0++) {
        #pragma unroll
        for (int i = 0; i < 2; i++) {
            int c = tid + i * 256, row = c >> 3, cs = c & 7, gc = cs ^ (row & 7);
            gl_lds16(Kg + t0 * 4096 + row * 64 + gc * 8, Ks[t0] + c * 8);
            gl_lds16(Vg + t0 * 4096 + row * 64 + gc * 8, Vs[t0] + c * 8);
        }
    }
    WAITCNT_VM(4);                     // Q loads + tile 0 landed; tile 1 in flight
    BARRIER_FENCED();

    f32x4 o[2][4];
    #pragma unroll
    for (int qs = 0; qs < 2; qs++)
        #pragma unroll
        for (int tn = 0; tn < 4; tn++) o[qs][tn] = (f32x4){0.f, 0.f, 0.f, 0.f};
    float lp[2] = {0.f, 0.f};

    const int ksw = lcol & 7;                        // K row-xor (row&7 = lcol&7)
    const int bq  = ((quad & 1) << 1) | (quad >> 1); // V chunk bit-reverse perm

    for (int kt = 0; kt < 32; kt++) {
        const int p = kt % 3;
        if (kt < 30) {                 // prefetch tile kt+2
            const int pb = (kt + 2) % 3;
            const short* Kn = Kg + (kt + 2) * 4096;
            const short* Vn = Vg + (kt + 2) * 4096;
            #pragma unroll
            for (int i = 0; i < 2; i++) {
                int c = tid + i * 256, row = c >> 3, cs = c & 7, gc = cs ^ (row & 7);
                gl_lds16(Kn + row * 64 + gc * 8, Ks[pb] + c * 8);
                gl_lds16(Vn + row * 64 + gc * 8, Vs[pb] + c * 8);
            }
        }

        // QK^T: wave's 32 q cols vs its 32 kv rows
        f32x4 st[2][2];
        #pragma unroll
        for (int kvs = 0; kvs < 2; kvs++)
            #pragma unroll
            for (int qs = 0; qs < 2; qs++) st[kvs][qs] = (f32x4){0.f, 0.f, 0.f, 0.f};
        #pragma unroll
        for (int ks = 0; ks < 2; ks++) {
            #pragma unroll
            for (int kvs = 0; kvs < 2; kvs++) {
                bf16x8 kf = *(const bf16x8*)(Ks[p] + (kh*32 + kvs*16 + lcol) * 64 +
                                             (((ks*4 + quad) ^ ksw) << 3));
                #pragma unroll
                for (int qs = 0; qs < 2; qs++)
                    st[kvs][qs] = __builtin_amdgcn_mfma_f32_16x16x32_bf16(kf, qf[qs][ks], st[kvs][qs], 0, 0, 0);
            }
        }

        // softmax numerators -> bf16 pairs (value for q = qs*16+lcol)
        uint32_t X[2][2], Y[2][2];
        #pragma unroll
        for (int kvs = 0; kvs < 2; kvs++) {
            #pragma unroll
            for (int qs = 0; qs < 2; qs++) {
                float p0 = exp2fast(st[kvs][qs][0]), p1 = exp2fast(st[kvs][qs][1]);
                float p2 = exp2fast(st[kvs][qs][2]), p3 = exp2fast(st[kvs][qs][3]);
                lp[qs] += (p0 + p1) + (p2 + p3);
                asm("v_cvt_pk_bf16_f32 %0, %1, %2" : "=v"(X[kvs][qs]) : "v"(p0), "v"(p1));
                asm("v_cvt_pk_bf16_f32 %0, %1, %2" : "=v"(Y[kvs][qs]) : "v"(p2), "v"(p3));
            }
        }

        // in-register transpose (R14-verified construction, per qs)
        bf16x8 pa[2];
        #pragma unroll
        for (int qs = 0; qs < 2; qs++) {
            uint32_t a0 = X[0][qs], a1 = X[1][qs];
            uint32_t b0 = Y[0][qs], b1 = Y[1][qs];
            asm("v_permlane16_swap_b32 %0, %1" : "+v"(a0), "+v"(a1));
            asm("v_permlane16_swap_b32 %0, %1" : "+v"(b0), "+v"(b1));
            union { uint32_t u[4]; bf16x8 v; } pk_;
            pk_.u[0] = a0; pk_.u[1] = b0; pk_.u[2] = a1; pk_.u[3] = b1;
            pa[qs] = pk_.v;
        }

        // PV: o[32 q rows][64 d] += P[32q][32kv] * V[32kv][64d]
        #pragma unroll
        for (int tn = 0; tn < 4; tn++) {
            int row = tn * 16 + lcol;
            bf16x8 bv = *(const bf16x8*)(Vs[p] + row * 64 +
                                         (((kh*4 + bq) ^ (row & 7)) << 3));
            #pragma unroll
            for (int qs = 0; qs < 2; qs++)
                o[qs][tn] = __builtin_amdgcn_mfma_f32_16x16x32_bf16(pa[qs], bv, o[qs][tn], 0, 0, 0);
        }

        if (kt < 31) {
            if (kt < 30) WAITCNT_VM(4);   // tile kt+1 landed, kt+2 in flight
            else         WAITCNT_VM(0);   // nothing new issued
            BARRIER_FENCED();
        }
    }

    // reduce lp across quads (wave's kv-half sum, per q = qs*16+lcol)
    #pragma unroll
    for (int qs = 0; qs < 2; qs++) {
        lp[qs] += __shfl_xor(lp[qs], 16, 64);
        lp[qs] += __shfl_xor(lp[qs], 32, 64);
    }

    // exchange partials between wave pairs (same qh, kh 0/1) via LDS scratch
    float* scr = (float*)&Ks[0][0];    // 18.4KB used of 24KB
    const int obase = qh * 2304;
    __syncthreads();                   // protect last-iter LDS reads
    if (kh) {
        #pragma unroll
        for (int qs = 0; qs < 2; qs++)
            #pragma unroll
            for (int tn = 0; tn < 4; tn++)
                *(f32x4*)(scr + obase + ((qs*4 + tn) * 64 + lane) * 4) = o[qs][tn];
        scr[obase + 2048 + lane*2 + 0] = lp[0];
        scr[obase + 2048 + lane*2 + 1] = lp[1];
    }
    __syncthreads();
    if (!kh) {
        #pragma unroll
        for (int qs = 0; qs < 2; qs++) {
            #pragma unroll
            for (int tn = 0; tn < 4; tn++) {
                f32x4 t = *(const f32x4*)(scr + obase + ((qs*4 + tn) * 64 + lane) * 4);
                o[qs][tn] += t;
            }
            lp[qs] += scr[obase + 2048 + lane*2 + qs];
        }
        #pragma unroll
        for (int qs = 0; qs < 2; qs++) {
            float rl[4];
            #pragma unroll
            for (int r = 0; r < 4; r++)
                rl[r] = 1.0f / __shfl(lp[qs], quad * 4 + r, 64);
            #pragma unroll
            for (int tn = 0; tn < 4; tn++) {
                #pragma unroll
                for (int r = 0; r < 4; r++) {
                    int q = qt * 64 + qh * 32 + qs * 16 + quad * 4 + r;
                    int d = h * 64 + tn * 16 + lcol;
                    Ab[((size_t)(b * 2048 + q)) * 768 + d] = f2bf(o[qs][tn][r] * rl[r]);
                }
            }
        }
    }
}

// ---------------------------------------------------------------------------
// out-proj GEMM (R13, proven): 64x96 tiles, 512 blocks = 2/CU, double-buffered.
// ---------------------------------------------------------------------------
__global__ __launch_bounds__(256)
void gemm_out(const short* __restrict__ A, const short* __restrict__ Bt,
              const float* __restrict__ bias, float* __restrict__ Of)
{
    __shared__ short As[2][64 * 32];   // 256 chunks each buffer
    __shared__ short Bs[2][96 * 32];   // 384 chunks
    const int tid = threadIdx.x, lane = tid & 63, w = tid >> 6;
    const int wm = w >> 1, wn = w & 1, quad = lane >> 4, lcol = lane & 15;
    const int bm = blockIdx.y * 64, bn = blockIdx.x * 96;

    f32x4 acc[2][3];
    #pragma unroll
    for (int i = 0; i < 2; i++)
        #pragma unroll
        for (int j = 0; j < 3; j++) acc[i][j] = (f32x4){0.f, 0.f, 0.f, 0.f};

    {
        int row = tid >> 2, cs = tid & 3;
        gl_lds16(A  + (size_t)(bm + row) * 768 + cs * 8, As[0] + tid * 8);
        gl_lds16(Bt + (size_t)(bn + row) * 768 + cs * 8, Bs[0] + tid * 8);
        if (tid < 128) {
            int c = 256 + tid, row2 = c >> 2, cs2 = c & 3;
            gl_lds16(Bt + (size_t)(bn + row2) * 768 + cs2 * 8, Bs[0] + c * 8);
        }
    }
    __syncthreads();

    for (int it = 0; it < 24; it++) {
        const int p = it & 1;
        if (it < 23) {
            int kt = (it + 1) * 32;
            int row = tid >> 2, cs = tid & 3;
            gl_lds16(A  + (size_t)(bm + row) * 768 + kt + cs * 8, As[p ^ 1] + tid * 8);
            gl_lds16(Bt + (size_t)(bn + row) * 768 + kt + cs * 8, Bs[p ^ 1] + tid * 8);
            if (tid < 128) {
                int c = 256 + tid, row2 = c >> 2, cs2 = c & 3;
                gl_lds16(Bt + (size_t)(bn + row2) * 768 + kt + cs2 * 8, Bs[p ^ 1] + c * 8);
            }
        }
        bf16x8 a[2], b[3];
        #pragma unroll
        for (int tm = 0; tm < 2; tm++)
            a[tm] = *(const bf16x8*)(As[p] + (wm*32 + tm*16 + lcol) * 32 + quad * 8);
        #pragma unroll
        for (int tn = 0; tn < 3; tn++)
            b[tn] = *(const bf16x8*)(Bs[p] + (wn*48 + tn*16 + lcol) * 32 + quad * 8);
        #pragma unroll
        for (int tm = 0; tm < 2; tm++)
            #pragma unroll
            for (int tn = 0; tn < 3; tn++)
                acc[tm][tn] = __builtin_amdgcn_mfma_f32_16x16x32_bf16(a[tm], b[tn], acc[tm][tn], 0, 0, 0);
        __syncthreads();
    }
    #pragma unroll
    for (int tm = 0; tm < 2; tm++) {
        #pragma unroll
        for (int tn = 0; tn < 3; tn++) {
            int col = bn + wn*48 + tn*16 + lcol;
            float bv = bias[col];
            #pragma unroll
            for (int reg = 0; reg < 4; reg++) {
                int row = bm + wm*32 + tm*16 + quad*4 + reg;
                Of[(size_t)row * 768 + col] = acc[tm][tn][reg] + bv;
            }
        }
    }
}

// ---------------------------------------------------------------------------
extern "C" void kernel_launch(void* const* d_in, const int* in_sizes, int n_in,
                              void* d_out, int out_size, void* d_ws, size_t ws_size,
                              hipStream_t stream)
{
    (void)in_sizes; (void)n_in; (void)out_size;
    const float* x     = (const float*)d_in[0];
    const float* w_qkv = (const float*)d_in[1];
    const float* b_qkv = (const float*)d_in[2];
    const float* w_out = (const float*)d_in[3];
    const float* b_out = (const float*)d_in[4];
    float* out = (float*)d_out;

    const size_t XSZ = (size_t)4096 * 768;
    const size_t WQ  = (size_t)2304 * 768;
    const size_t WO  = (size_t)768 * 768;
    const size_t HSZ = (size_t)24 * 2048 * 64;
    short* Xb  = (short*)d_ws;
    short* Wqt = Xb + XSZ;
    short* Qb  = Wqt + WQ;
    short* Kb  = Qb + HSZ;
    short* Vt  = Kb + HSZ;
    short* Ab  = Xb;                       // x dead after gemm_qkv

    const bool sepWot = ws_size >= (XSZ + WQ + 3*HSZ + WO) * sizeof(short);
    short* Wot = sepWot ? (Vt + HSZ) : Wqt;   // else alias (w_qkv^T dead after gemm0)

    if (sepWot) {
        prep_k<<<2112, 256, 0, stream>>>(x, Xb, w_qkv, Wqt, w_out, Wot);
        gemm_qkv<<<dim3(24, 32), 256, 0, stream>>>(Xb, Wqt, b_qkv, Qb, Kb, Vt);
    } else {
        prep_k<<<1968, 256, 0, stream>>>(x, Xb, w_qkv, Wqt, w_out, Wot);
        gemm_qkv<<<dim3(24, 32), 256, 0, stream>>>(Xb, Wqt, b_qkv, Qb, Kb, Vt);
        tr_w<<<dim3(12, 12), 256, 0, stream>>>(w_out, Wot, 768, 768);
    }
    attn_k<<<768, 256, 0, stream>>>(Qb, Kb, Vt, Ab);
    gemm_out<<<dim3(8, 64), 256, 0, stream>>>(Ab, Wot, b_out, out);
}

// Round 4
// 156.645 us; speedup vs baseline: 1.0522x; 1.0522x over previous
//
#include <hip/hip_runtime.h>
#include <hip/hip_bf16.h>
#include <stdint.h>

// Attention fwd: B=2, N=2048, D=768, H=12, Dh=64, INNER=768
// R17 = best-measured recombination + two proven-prior changes:
//  * attn_k: R15 form (44.2us measured; R16 kv-split REVERTED -- halving LDS
//    reads made it slower, so attn is latency-bound not LDS-bound)
//    + T5 s_setprio(1) around QK and PV MFMA clusters (attn-proven +4-7%).
//  * gemm_qkv / gemm_out: R13 structure + CLEAN counted-vmcnt triple-buffer
//    (distance 2). R15's version regressed because it duplicated 33% of the
//    B-tile DMA to force wave-uniform counts; but counts are ALREADY wave-
//    uniform (waves 0-1: 4/tile, waves 2-3: 3/tile) -- select the vmcnt
//    literal with a wave-uniform branch. No extra traffic, loads stay in
//    flight across barriers (m218: counted-vs-drain0 is the big lever).

typedef __attribute__((ext_vector_type(8))) short bf16x8;
typedef __attribute__((ext_vector_type(4))) float f32x4;
typedef __attribute__((address_space(3))) unsigned int lds_uint;
typedef __attribute__((address_space(1))) const unsigned int g_uint;

__device__ __forceinline__ short f2bf(float f) {
    union { float f; uint32_t u; } x; x.f = f;
    uint32_t r = (x.u + 0x7fffu + ((x.u >> 16) & 1u)) >> 16;
    return (short)r;
}
__device__ __forceinline__ float exp2fast(float x) {
#if __has_builtin(__builtin_amdgcn_exp2f)
    return __builtin_amdgcn_exp2f(x);
#else
    return __expf(x * 0.6931471805599453f);
#endif
}
__device__ __forceinline__ void gl_lds16(const void* g, void* l) {
    __builtin_amdgcn_global_load_lds((g_uint*)g, (lds_uint*)l, 16, 0, 0);
}
#define WAITCNT_VM(N) asm volatile("s_waitcnt vmcnt(" #N ")" ::: "memory")
#define BARRIER_FENCED() do { __builtin_amdgcn_s_barrier(); \
                              asm volatile("" ::: "memory"); } while (0)

// ---------------------------------------------------------------------------
// 64x64 fp32->bf16 transpose tile (shared by prep_k / tr_w)
// ---------------------------------------------------------------------------
__device__ __forceinline__ void tr_tile(const float* __restrict__ W,
                                        short* __restrict__ Wt, int K, int N,
                                        int n0, int k0, int t, short* S) {
    {
        int kl = t >> 2, ng = t & 3;
        const float* src = W + (size_t)(k0 + kl) * N + n0 + ng * 16;
        #pragma unroll
        for (int j = 0; j < 16; j += 4) {
            float4 f = *(const float4*)(src + j);
            S[(ng*16 + j + 0) * 65 + kl] = f2bf(f.x);
            S[(ng*16 + j + 1) * 65 + kl] = f2bf(f.y);
            S[(ng*16 + j + 2) * 65 + kl] = f2bf(f.z);
            S[(ng*16 + j + 3) * 65 + kl] = f2bf(f.w);
        }
    }
    __syncthreads();
    {
        int nl = t >> 2, kg = t & 3;
        short* dst = Wt + (size_t)(n0 + nl) * K + k0 + kg * 16;
        #pragma unroll
        for (int j = 0; j < 16; j += 4) {
            short4 s4;
            s4.x = S[nl*65 + kg*16 + j + 0];
            s4.y = S[nl*65 + kg*16 + j + 1];
            s4.z = S[nl*65 + kg*16 + j + 2];
            s4.w = S[nl*65 + kg*16 + j + 3];
            *(short4*)(dst + j) = s4;
        }
    }
}

// fused prep: [0,1536) x->bf16 ; [1536,1968) w_qkv^T ; [1968,2112) w_out^T
__global__ __launch_bounds__(256)
void prep_k(const float* __restrict__ x, short* __restrict__ Xb,
            const float* __restrict__ Wq, short* __restrict__ Wqt,
            const float* __restrict__ Wo, short* __restrict__ Wot)
{
    __shared__ short S[64 * 65];
    const int t = threadIdx.x;
    if (blockIdx.x < 1536) {
        int i = (blockIdx.x * 256 + t) * 8;
        float4 f0 = *(const float4*)(x + i);
        float4 f1 = *(const float4*)(x + i + 4);
        short s[8];
        s[0]=f2bf(f0.x); s[1]=f2bf(f0.y); s[2]=f2bf(f0.z); s[3]=f2bf(f0.w);
        s[4]=f2bf(f1.x); s[5]=f2bf(f1.y); s[6]=f2bf(f1.z); s[7]=f2bf(f1.w);
        *(uint4*)(Xb + i) = *(uint4*)s;
        return;
    }
    if (blockIdx.x < 1968) {
        const int b2 = blockIdx.x - 1536;                  // N=2304, K=768
        tr_tile(Wq, Wqt, 768, 2304, (b2 % 36) * 64, (b2 / 36) * 64, t, S);
    } else {
        const int b3 = blockIdx.x - 1968;                  // N=768, K=768
        tr_tile(Wo, Wot, 768, 768, (b3 % 12) * 64, (b3 / 12) * 64, t, S);
    }
}

// standalone w_out transpose (fallback when Wot must alias Wqt)
__global__ __launch_bounds__(256)
void tr_w(const float* __restrict__ W, short* __restrict__ Wt, int K, int N) {
    __shared__ short S[64 * 65];
    tr_tile(W, Wt, K, N, blockIdx.x * 64, blockIdx.y * 64, threadIdx.x, S);
}

// ---------------------------------------------------------------------------
// QKV GEMM R17: 128x96 tiles, 768 blocks = 3/CU, triple-buffered DMA staging,
// prefetch distance 2, counted vmcnt WITHOUT traffic duplication:
// waves 0-1 issue 4 loads/tile, waves 2-3 issue 3 -> wave-uniform branch
// picks vmcnt(4)/vmcnt(3). LDS 42KB -> still 3 blocks/CU.
// [4096x768]bf16 @ Wqt[2304x768]^T + b -> Qb(pre-scaled)/Kb/Vt bf16
// ---------------------------------------------------------------------------
__global__ __launch_bounds__(256)
void gemm_qkv(const short* __restrict__ A, const short* __restrict__ Bt,
              const float* __restrict__ bias,
              short* __restrict__ Qb, short* __restrict__ Kb, short* __restrict__ Vt)
{
    __shared__ short As[3][128 * 32];  // 512 chunks of 16B per buffer (24KB)
    __shared__ short Bs[3][96 * 32];   // 384 chunks per buffer (18KB)
    const int tid = threadIdx.x, lane = tid & 63, w = tid >> 6;
    const int wm = w >> 1, wn = w & 1, quad = lane >> 4, lcol = lane & 15;
    const int bm = blockIdx.y * 128, bn = blockIdx.x * 96;

    f32x4 acc[4][3];
    #pragma unroll
    for (int i = 0; i < 4; i++)
        #pragma unroll
        for (int j = 0; j < 3; j++) acc[i][j] = (f32x4){0.f, 0.f, 0.f, 0.f};

    const int ar0 = tid >> 2,         ac0 = (tid & 3) * 8;
    const int ar1 = (tid + 256) >> 2;
    const int c2  = 256 + tid;         // only tid<128 uses it
    const int br1 = c2 >> 2,          bc1 = (c2 & 3) * 8;

    #pragma unroll
    for (int t0 = 0; t0 < 2; t0++) {   // stage tiles 0,1
        const int kt = t0 * 32;
        gl_lds16(A  + (size_t)(bm + ar0) * 768 + kt + ac0, As[t0] + tid * 8);
        gl_lds16(A  + (size_t)(bm + ar1) * 768 + kt + ac0, As[t0] + (tid + 256) * 8);
        gl_lds16(Bt + (size_t)(bn + ar0) * 768 + kt + ac0, Bs[t0] + tid * 8);
        if (tid < 128)
            gl_lds16(Bt + (size_t)(bn + br1) * 768 + kt + bc1, Bs[t0] + c2 * 8);
    }
    if (w < 2) { WAITCNT_VM(4); } else { WAITCNT_VM(3); }   // tile0 done, tile1 in flight
    BARRIER_FENCED();

    for (int it = 0; it < 24; it++) {
        const int p = it % 3;
        if (it < 22) {                 // prefetch tile it+2
            const int pb = (it + 2) % 3, kt = (it + 2) * 32;
            gl_lds16(A  + (size_t)(bm + ar0) * 768 + kt + ac0, As[pb] + tid * 8);
            gl_lds16(A  + (size_t)(bm + ar1) * 768 + kt + ac0, As[pb] + (tid + 256) * 8);
            gl_lds16(Bt + (size_t)(bn + ar0) * 768 + kt + ac0, Bs[pb] + tid * 8);
            if (tid < 128)
                gl_lds16(Bt + (size_t)(bn + br1) * 768 + kt + bc1, Bs[pb] + c2 * 8);
        }
        bf16x8 a[4], b[3];
        #pragma unroll
        for (int tm = 0; tm < 4; tm++)
            a[tm] = *(const bf16x8*)(As[p] + (wm*64 + tm*16 + lcol) * 32 + quad * 8);
        #pragma unroll
        for (int tn = 0; tn < 3; tn++)
            b[tn] = *(const bf16x8*)(Bs[p] + (wn*48 + tn*16 + lcol) * 32 + quad * 8);
        #pragma unroll
        for (int tm = 0; tm < 4; tm++)
            #pragma unroll
            for (int tn = 0; tn < 3; tn++)
                acc[tm][tn] = __builtin_amdgcn_mfma_f32_16x16x32_bf16(a[tm], b[tn], acc[tm][tn], 0, 0, 0);
        if (it < 23) {
            if (it < 22) {             // tile it+1 landed, it+2 stays in flight
                if (w < 2) { WAITCNT_VM(4); } else { WAITCNT_VM(3); }
            } else {
                WAITCNT_VM(0);         // drain last staged tile
            }
            BARRIER_FENCED();
        }
    }

    const float SCLQ = 0.18033688011112042f;   // 0.125 * log2(e) folded into Q
    #pragma unroll
    for (int tm = 0; tm < 4; tm++) {
        #pragma unroll
        for (int tn = 0; tn < 3; tn++) {
            int col = bn + wn*48 + tn*16 + lcol;
            float bv = bias[col];
            int which = (col >= 1536) ? 2 : (col >= 768 ? 1 : 0);
            int cc = col - which * 768;
            int h = cc >> 6, d = cc & 63;
            int rowbase = bm + wm*64 + tm*16 + quad*4;
            int bb = rowbase >> 11, n0 = rowbase & 2047;
            int bh = bb * 12 + h;
            if (which == 2) {                 // V: tiled V^T store, dense window
                short4 s4;
                s4.x = f2bf(acc[tm][tn][0] + bv);
                s4.y = f2bf(acc[tm][tn][1] + bv);
                s4.z = f2bf(acc[tm][tn][2] + bv);
                s4.w = f2bf(acc[tm][tn][3] + bv);
                *(short4*)(Vt + (((size_t)bh*32 + (n0 >> 6))*64 + d)*64 + (n0 & 63)) = s4;
            } else {
                #pragma unroll
                for (int reg = 0; reg < 4; reg++) {
                    float v = acc[tm][tn][reg] + bv;
                    if (which == 0) v *= SCLQ;
                    short* dst = (which == 0) ? Qb : Kb;
                    dst[((size_t)bh*2048 + n0 + reg)*64 + d] = f2bf(v);
                }
            }
        }
    }
}

// ---------------------------------------------------------------------------
// Flash attention R17 = R15 (measured best, 44.2us) + T5 setprio around the
// QK and PV MFMA clusters. Per-wave q-ownership, in-register P transpose,
// triple-buffered K/V staging with counted vmcnt(4), 1 barrier/iter.
// ---------------------------------------------------------------------------
__global__ __launch_bounds__(256)
void attn_k(const short* __restrict__ Q, const short* __restrict__ K,
            const short* __restrict__ Vt, short* __restrict__ Ab)
{
    __shared__ __align__(16) short Ks[3][4096];   // [kv][d] xor-swizzled chunks
    __shared__ __align__(16) short Vs[3][4096];   // [d][kv] xor-swizzled chunks

    const int tid = threadIdx.x, lane = tid & 63, w = tid >> 6;
    const int quad = lane >> 4, lcol = lane & 15;
    const int bid = blockIdx.x;
    const int bh = bid % 24, qt = bid / 24;
    const int b = bh / 12, h = bh - b * 12;

    const short* Kg = K  + (size_t)bh * 131072;   // [n][d] rows, tile = 8KB
    const short* Vg = Vt + (size_t)bh * 131072;   // tiled [kt][d][n64], 8KB

    bf16x8 qf[2];                       // this wave's 16 q rows only
    {
        const short* Qg = Q + ((size_t)bh * 2048 + (size_t)qt * 64) * 64;
        #pragma unroll
        for (int ks = 0; ks < 2; ks++)
            qf[ks] = *(const bf16x8*)(Qg + (w*16 + lcol) * 64 + ks*32 + quad*8);
    }

    // stage tiles 0,1 (4 loads/thread/tile, uniform)
    #pragma unroll
    for (int t0 = 0; t0 < 2; t0++) {
        #pragma unroll
        for (int i = 0; i < 2; i++) {
            int c = tid + i * 256, row = c >> 3, cs = c & 7, gc = cs ^ (row & 7);
            gl_lds16(Kg + t0 * 4096 + row * 64 + gc * 8, Ks[t0] + c * 8);
            gl_lds16(Vg + t0 * 4096 + row * 64 + gc * 8, Vs[t0] + c * 8);
        }
    }
    WAITCNT_VM(4);                     // Q loads + tile 0 landed; tile 1 in flight
    BARRIER_FENCED();

    f32x4 o[4];
    #pragma unroll
    for (int tn = 0; tn < 4; tn++) o[tn] = (f32x4){0.f, 0.f, 0.f, 0.f};
    float lp = 0.f;

    const int ksw = lcol & 7;                       // K row-xor ((kvs*16+lcol)&7)
    const int bq  = ((quad & 1) << 1) | (quad >> 1); // V chunk bit-reverse perm

    for (int kt = 0; kt < 32; kt++) {
        const int p = kt % 3;
        if (kt < 30) {                 // prefetch tile kt+2
            const int pb = (kt + 2) % 3;
            const short* Kn = Kg + (kt + 2) * 4096;
            const short* Vn = Vg + (kt + 2) * 4096;
            #pragma unroll
            for (int i = 0; i < 2; i++) {
                int c = tid + i * 256, row = c >> 3, cs = c & 7, gc = cs ^ (row & 7);
                gl_lds16(Kn + row * 64 + gc * 8, Ks[pb] + c * 8);
                gl_lds16(Vn + row * 64 + gc * 8, Vs[pb] + c * 8);
            }
        }

        // QK^T: wave's 16 q cols vs all 64 kv rows
        f32x4 st[4];
        #pragma unroll
        for (int kvs = 0; kvs < 4; kvs++) st[kvs] = (f32x4){0.f, 0.f, 0.f, 0.f};
        __builtin_amdgcn_s_setprio(1);
        #pragma unroll
        for (int ks = 0; ks < 2; ks++) {
            #pragma unroll
            for (int kvs = 0; kvs < 4; kvs++) {
                bf16x8 kf = *(const bf16x8*)(Ks[p] + (kvs*16 + lcol) * 64 +
                                             (((ks*4 + quad) ^ ksw) << 3));
                st[kvs] = __builtin_amdgcn_mfma_f32_16x16x32_bf16(kf, qf[ks], st[kvs], 0, 0, 0);
            }
        }
        __builtin_amdgcn_s_setprio(0);

        // softmax numerators -> bf16 pairs (all values belong to q = w*16+lcol)
        uint32_t X[4], Y[4];
        #pragma unroll
        for (int kvs = 0; kvs < 4; kvs++) {
            float p0 = exp2fast(st[kvs][0]), p1 = exp2fast(st[kvs][1]);
            float p2 = exp2fast(st[kvs][2]), p3 = exp2fast(st[kvs][3]);
            lp += (p0 + p1) + (p2 + p3);
            asm("v_cvt_pk_bf16_f32 %0, %1, %2" : "=v"(X[kvs]) : "v"(p0), "v"(p1));
            asm("v_cvt_pk_bf16_f32 %0, %1, %2" : "=v"(Y[kvs]) : "v"(p2), "v"(p3));
        }

        // in-register transpose to PV A-fragments (one swap fills two dwords)
        bf16x8 pa[2];
        #pragma unroll
        for (int ks = 0; ks < 2; ks++) {
            uint32_t a0 = X[2*ks], a1 = X[2*ks + 1];
            uint32_t b0 = Y[2*ks], b1 = Y[2*ks + 1];
            asm("v_permlane16_swap_b32 %0, %1" : "+v"(a0), "+v"(a1));
            asm("v_permlane16_swap_b32 %0, %1" : "+v"(b0), "+v"(b1));
            union { uint32_t u[4]; bf16x8 v; } pk_;
            pk_.u[0] = a0; pk_.u[1] = b0; pk_.u[2] = a1; pk_.u[3] = b1;
            pa[ks] = pk_.v;
        }

        // PV: o[q rows of this wave][d] += P * V
        __builtin_amdgcn_s_setprio(1);
        #pragma unroll
        for (int ks = 0; ks < 2; ks++) {
            #pragma unroll
            for (int tn = 0; tn < 4; tn++) {
                int row = tn * 16 + lcol;
                bf16x8 bv = *(const bf16x8*)(Vs[p] + row * 64 +
                                             (((ks*4 + bq) ^ (row & 7)) << 3));
                o[tn] = __builtin_amdgcn_mfma_f32_16x16x32_bf16(pa[ks], bv, o[tn], 0, 0, 0);
            }
        }
        __builtin_amdgcn_s_setprio(0);

        if (kt < 31) {
            if (kt < 30) WAITCNT_VM(4);   // tile kt+1 landed, kt+2 in flight
            else         WAITCNT_VM(0);   // tile 31 (nothing new issued)
            BARRIER_FENCED();
        }
    }

    // row-sum: kv-split is across quads of the SAME wave -> pure shuffles
    lp += __shfl_xor(lp, 16, 64);
    lp += __shfl_xor(lp, 32, 64);
    float rl[4];
    #pragma unroll
    for (int r = 0; r < 4; r++)
        rl[r] = 1.0f / __shfl(lp, quad * 4 + r, 64);   // lane lcol=q' holds sum(q')

    #pragma unroll
    for (int tn = 0; tn < 4; tn++) {
        #pragma unroll
        for (int r = 0; r < 4; r++) {
            int q = qt * 64 + w * 16 + quad * 4 + r;
            int d = h * 64 + tn * 16 + lcol;
            Ab[((size_t)(b * 2048 + q)) * 768 + d] = f2bf(o[tn][r] * rl[r]);
        }
    }
}

// ---------------------------------------------------------------------------
// out-proj GEMM R17: 64x96 tiles, 512 blocks = 2/CU, triple-buffered DMA,
// prefetch distance 2, counted vmcnt (waves 0-1: 3 loads/tile, waves 2-3: 2).
// ---------------------------------------------------------------------------
__global__ __launch_bounds__(256)
void gemm_out(const short* __restrict__ A, const short* __restrict__ Bt,
              const float* __restrict__ bias, float* __restrict__ Of)
{
    __shared__ short As[3][64 * 32];   // 256 chunks per buffer (12KB)
    __shared__ short Bs[3][96 * 32];   // 384 chunks per buffer (18KB)
    const int tid = threadIdx.x, lane = tid & 63, w = tid >> 6;
    const int wm = w >> 1, wn = w & 1, quad = lane >> 4, lcol = lane & 15;
    const int bm = blockIdx.y * 64, bn = blockIdx.x * 96;

    f32x4 acc[2][3];
    #pragma unroll
    for (int i = 0; i < 2; i++)
        #pragma unroll
        for (int j = 0; j < 3; j++) acc[i][j] = (f32x4){0.f, 0.f, 0.f, 0.f};

    const int ar0 = tid >> 2, ac0 = (tid & 3) * 8;
    const int c2  = 256 + tid;         // only tid<128 uses it
    const int br1 = c2 >> 2,  bc1 = (c2 & 3) * 8;

    #pragma unroll
    for (int t0 = 0; t0 < 2; t0++) {   // stage tiles 0,1
        const int kt = t0 * 32;
        gl_lds16(A  + (size_t)(bm + ar0) * 768 + kt + ac0, As[t0] + tid * 8);
        gl_lds16(Bt + (size_t)(bn + ar0) * 768 + kt + ac0, Bs[t0] + tid * 8);
        if (tid < 128)
            gl_lds16(Bt + (size_t)(bn + br1) * 768 + kt + bc1, Bs[t0] + c2 * 8);
    }
    if (w < 2) { WAITCNT_VM(3); } else { WAITCNT_VM(2); }
    BARRIER_FENCED();

    for (int it = 0; it < 24; it++) {
        const int p = it % 3;
        if (it < 22) {
            const int pb = (it + 2) % 3, kt = (it + 2) * 32;
            gl_lds16(A  + (size_t)(bm + ar0) * 768 + kt + ac0, As[pb] + tid * 8);
            gl_lds16(Bt + (size_t)(bn + ar0) * 768 + kt + ac0, Bs[pb] + tid * 8);
            if (tid < 128)
                gl_lds16(Bt + (size_t)(bn + br1) * 768 + kt + bc1, Bs[pb] + c2 * 8);
        }
        bf16x8 a[2], b[3];
        #pragma unroll
        for (int tm = 0; tm < 2; tm++)
            a[tm] = *(const bf16x8*)(As[p] + (wm*32 + tm*16 + lcol) * 32 + quad * 8);
        #pragma unroll
        for (int tn = 0; tn < 3; tn++)
            b[tn] = *(const bf16x8*)(Bs[p] + (wn*48 + tn*16 + lcol) * 32 + quad * 8);
        #pragma unroll
        for (int tm = 0; tm < 2; tm++)
            #pragma unroll
            for (int tn = 0; tn < 3; tn++)
                acc[tm][tn] = __builtin_amdgcn_mfma_f32_16x16x32_bf16(a[tm], b[tn], acc[tm][tn], 0, 0, 0);
        if (it < 23) {
            if (it < 22) {
                if (w < 2) { WAITCNT_VM(3); } else { WAITCNT_VM(2); }
            } else {
                WAITCNT_VM(0);
            }
            BARRIER_FENCED();
        }
    }
    #pragma unroll
    for (int tm = 0; tm < 2; tm++) {
        #pragma unroll
        for (int tn = 0; tn < 3; tn++) {
            int col = bn + wn*48 + tn*16 + lcol;
            float bv = bias[col];
            #pragma unroll
            for (int reg = 0; reg < 4; reg++) {
                int row = bm + wm*32 + tm*16 + quad*4 + reg;
                Of[(size_t)row * 768 + col] = acc[tm][tn][reg] + bv;
            }
        }
    }
}

// ---------------------------------------------------------------------------
extern "C" void kernel_launch(void* const* d_in, const int* in_sizes, int n_in,
                              void* d_out, int out_size, void* d_ws, size_t ws_size,
                              hipStream_t stream)
{
    (void)in_sizes; (void)n_in; (void)out_size;
    const float* x     = (const float*)d_in[0];
    const float* w_qkv = (const float*)d_in[1];
    const float* b_qkv = (const float*)d_in[2];
    const float* w_out = (const float*)d_in[3];
    const float* b_out = (const float*)d_in[4];
    float* out = (float*)d_out;

    const size_t XSZ = (size_t)4096 * 768;
    const size_t WQ  = (size_t)2304 * 768;
    const size_t WO  = (size_t)768 * 768;
    const size_t HSZ = (size_t)24 * 2048 * 64;
    short* Xb  = (short*)d_ws;
    short* Wqt = Xb + XSZ;
    short* Qb  = Wqt + WQ;
    short* Kb  = Qb + HSZ;
    short* Vt  = Kb + HSZ;
    short* Ab  = Xb;                       // x dead after gemm_qkv

    const bool sepWot = ws_size >= (XSZ + WQ + 3*HSZ + WO) * sizeof(short);
    short* Wot = sepWot ? (Vt + HSZ) : Wqt;   // else alias (w_qkv^T dead after gemm0)

    if (sepWot) {
        prep_k<<<2112, 256, 0, stream>>>(x, Xb, w_qkv, Wqt, w_out, Wot);
        gemm_qkv<<<dim3(24, 32), 256, 0, stream>>>(Xb, Wqt, b_qkv, Qb, Kb, Vt);
    } else {
        prep_k<<<1968, 256, 0, stream>>>(x, Xb, w_qkv, Wqt, w_out, Wot);
        gemm_qkv<<<dim3(24, 32), 256, 0, stream>>>(Xb, Wqt, b_qkv, Qb, Kb, Vt);
        tr_w<<<dim3(12, 12), 256, 0, stream>>>(w_out, Wot, 768, 768);
    }
    attn_k<<<768, 256, 0, stream>>>(Qb, Kb, Vt, Ab);
    gemm_out<<<dim3(8, 64), 256, 0, stream>>>(Ab, Wot, b_out, out);
}